// Round 10
// baseline (8048.109 us; speedup 1.0000x reference)
//
#include <hip/hip_runtime.h>
#include <hip/hip_bf16.h>

typedef __attribute__((ext_vector_type(8))) short short8;
typedef __attribute__((ext_vector_type(4))) float float4v;

__device__ __forceinline__ float bf2f(short b) {
    unsigned u = ((unsigned)(unsigned short)b) << 16;
    union { unsigned u; float f; } c; c.u = u; return c.f;
}
__device__ __forceinline__ short f2bf(float f) {
    union { float f; unsigned u; } c; c.f = f;
    unsigned r = 0x7FFFu + ((c.u >> 16) & 1u);
    return (short)((c.u + r) >> 16);
}
// dtype-dispatched scalar load (flag: false=bf16, true=fp32)
__device__ __forceinline__ float ldf(const void* p, size_t i, bool f32) {
    return f32 ? ((const float*)p)[i] : bf2f(((const short*)p)[i]);
}
// dtype-dispatched 8-element MFMA fragment load; f32 path VECTORIZED (2x float4)
__device__ __forceinline__ short8 frag8(const void* p, size_t i, bool f32) {
    short8 r;
    if (f32) {
        const float* q = (const float*)p + i;     // i always 8-aligned at call sites
        float4v a = *(const float4v*)q;
        float4v b = *(const float4v*)(q + 4);
#pragma unroll
        for (int j = 0; j < 4; j++) { r[j] = f2bf(a[j]); r[4 + j] = f2bf(b[j]); }
    } else {
        r = *(const short8*)((const short*)p + i);
    }
    return r;
}

// ---------------- dtype detector: 0 = bf16, 1 = fp32 ----------------
__global__ void detect_dtype(const unsigned short* __restrict__ in, unsigned* __restrict__ flag)
{
    int t = threadIdx.x;  // 64 threads
    int sane = 0;
    for (int i = t; i < 256; i += 64) {
        unsigned e = (in[i] >> 7) & 0xFF;
        sane += (e >= 0x70 && e <= 0x8A) ? 1 : 0;
    }
#pragma unroll
    for (int o = 32; o > 0; o >>= 1) sane += __shfl_down(sane, o);
    if (t == 0) *flag = (sane >= 200) ? 0u : 1u;
}

// ---------------- init scratch (h ping-pong planes + flags) ----------------
__global__ void init_scratch(short* __restrict__ hb, unsigned* __restrict__ cnt)
{
    int i = blockIdx.x * 256 + threadIdx.x;
    if (i < 4 * 65536) hb[i] = 0;
    if (i < 512) cnt[i] = 0;
}

// ---------------- C = A @ B^T + bias, bf16 MFMA, optional fp32 hi/lo split --------
__global__ __launch_bounds__(256, 1) void gemm_bt(
    const void* __restrict__ A, const void* __restrict__ B,
    const void* __restrict__ bias, void* __restrict__ outbase, size_t coff,
    const unsigned* __restrict__ flag, int M, int N, int K)
{
    const bool f32 = flag && (flag[0] != 0u);
    __shared__ short Ah[128][72], Bh[128][72];
    __shared__ short Al[128][72], Bl[128][72];
    const int tid  = threadIdx.x;
    const int wid  = tid >> 6;
    const int lane = tid & 63;
    const int ln = lane & 15, q = lane >> 4;
    const int bm = blockIdx.x * 128, bn = blockIdx.y * 128;
    const int wm = (wid & 1) * 64, wn = (wid >> 1) * 64;

    float4v acc[4][4];
#pragma unroll
    for (int i = 0; i < 4; i++)
#pragma unroll
        for (int j = 0; j < 4; j++) acc[i][j] = (float4v){0.f, 0.f, 0.f, 0.f};

    for (int k0 = 0; k0 < K; k0 += 64) {
#pragma unroll
        for (int c = 0; c < 4; c++) {
            int chunk = tid + c * 256;
            int row = chunk >> 3;
            int kq  = (chunk & 7) * 8;
            size_t ga = (size_t)(bm + row) * K + k0 + kq;
            size_t gb = (size_t)(bn + row) * K + k0 + kq;
            if (f32) {
                const float* Af = (const float*)A;
                const float* Bf = (const float*)B;
#pragma unroll
                for (int j = 0; j < 8; j++) {
                    float av = Af[ga + j], bv = Bf[gb + j];
                    short ah = f2bf(av), bh = f2bf(bv);
                    Ah[row][kq + j] = ah; Al[row][kq + j] = f2bf(av - bf2f(ah));
                    Bh[row][kq + j] = bh; Bl[row][kq + j] = f2bf(bv - bf2f(bh));
                }
            } else {
                *(short8*)&Ah[row][kq] = *(const short8*)((const short*)A + ga);
                *(short8*)&Bh[row][kq] = *(const short8*)((const short*)B + gb);
            }
        }
        __syncthreads();
#pragma unroll
        for (int kt = 0; kt < 2; kt++) {
            short8 avh[4], bvh[4];
#pragma unroll
            for (int i = 0; i < 4; i++) avh[i] = *(const short8*)&Ah[wm + i * 16 + ln][kt * 32 + q * 8];
#pragma unroll
            for (int j = 0; j < 4; j++) bvh[j] = *(const short8*)&Bh[wn + j * 16 + ln][kt * 32 + q * 8];
#pragma unroll
            for (int i = 0; i < 4; i++)
#pragma unroll
                for (int j = 0; j < 4; j++)
                    acc[i][j] = __builtin_amdgcn_mfma_f32_16x16x32_bf16(avh[i], bvh[j], acc[i][j], 0, 0, 0);
            if (f32) {
                short8 avl[4], bvl[4];
#pragma unroll
                for (int i = 0; i < 4; i++) avl[i] = *(const short8*)&Al[wm + i * 16 + ln][kt * 32 + q * 8];
#pragma unroll
                for (int j = 0; j < 4; j++) bvl[j] = *(const short8*)&Bl[wn + j * 16 + ln][kt * 32 + q * 8];
#pragma unroll
                for (int i = 0; i < 4; i++)
#pragma unroll
                    for (int j = 0; j < 4; j++) {
                        acc[i][j] = __builtin_amdgcn_mfma_f32_16x16x32_bf16(avh[i], bvl[j], acc[i][j], 0, 0, 0);
                        acc[i][j] = __builtin_amdgcn_mfma_f32_16x16x32_bf16(avl[i], bvh[j], acc[i][j], 0, 0, 0);
                    }
            }
        }
        __syncthreads();
    }
    // C/D layout: col = lane&15, row = (lane>>4)*4 + reg
#pragma unroll
    for (int j = 0; j < 4; j++) {
        int col = bn + wn + j * 16 + ln;
        float bvv = ldf(bias, col, f32);
#pragma unroll
        for (int i = 0; i < 4; i++) {
#pragma unroll
            for (int r = 0; r < 4; r++) {
                int row = bm + wm + i * 16 + q * 4 + r;
                size_t idx = coff + (size_t)row * N + col;
                float v = acc[i][j][r] + bvv;
                if (f32) ((float*)outbase)[idx] = v;
                else     ((short*)outbase)[idx] = f2bf(v);
            }
        }
    }
}

// ---------------- persistent GRU recurrence: 8 groups x 8 rows, 2 WGs/CU -------
// R8 proved the latency model: smaller sync span => proportional speedup. Now:
// 8 batch groups x 8 rows, 64 col-WGs each = 512 WGs -> 2 WGs/CU (LDS 45KB x2,
// 6 waves/CU, VGPR capped 256 via launch_bounds). Co-resident WGs are from
// DIFFERENT groups (gb = w>>6; co-located pairs differ by ~256 under %8 XCD
// striping) -> one computes while the other waits: latency hiding via TLP.
// Per step, per WG: x 8KB + h 32KB (hi+lo merged, ONE load phase), M=8 rows of
// the 16x16 MFMA tile (half-waste, irrelevant at ~5% MfmaUtil).
// h planes (sc1/IC): [phase][pl][group][kb=128][r=8][8] shorts.
// Flags: single-slot monotone cnt[group*64+c] = t+1 (512 u32; poll = one 256B line).
// Protocol correctness: consumer polls >=t before reading phase (t&1); producer
// overwrites a phase only at t+2 after polling >=t+2, which members post only
// after their reads of that phase retired (reg-staged before vmcnt+flag). Zero
// fences; h-out stores confined to wave 0 so its vmcnt(0) drains them all.
#define NWG 512
__global__ __launch_bounds__(192, 2) void gru_rec(
    const void* __restrict__ inputs,   // (64,512,512)
    const void* __restrict__ Wx,       // (3072,512)
    const void* __restrict__ bx,       // 3072
    const void* __restrict__ Wh,       // (3072,1024)
    const void* __restrict__ bh,       // 3072
    short* __restrict__ hb,            // 512 KB h planes
    unsigned* __restrict__ cnt,        // 512 u32 flags (zeroed)
    const unsigned* __restrict__ flag, // dtype flag (may be null -> bf16)
    void* __restrict__ hid)            // (64,512,1024) output 0
{
    const bool f32 = flag && (flag[0] != 0u);
    __shared__ short xs[4096];         // 8 KB: [kb=64][r=8][8], r-swizzled
    __shared__ short hs[2][8192];      // 32 KB: [pl][kb=128][r=8][8], r-swizzled
    __shared__ float Px[3][8][17];
    __shared__ float Ph[3][8][17];
    __shared__ float hown[8][17];
    __shared__ float bxs[3][16], bhs[3][16];

    const int tid  = threadIdx.x;
    const int w    = blockIdx.x;
    const int gb   = w >> 6;           // batch group 0..7 (rows gb*8 .. gb*8+7)
    const int c    = w & 63;           // column WG (H cols c*16 .. c*16+15 per gate)
    const int g    = tid >> 6;         // 0..2 (gate / wave)
    const int lane = tid & 63;
    const int ln   = lane & 15, q = lane >> 4;
    const int lr   = ln & 7;           // A-row (rows 8-15 duplicate 0-7; outputs unused)

    // Wh / Wx B-fragments in registers: B[k][n]: n=lane&15, k=(lane>>4)*8+j
    const size_t whbase = (size_t)(g * 1024 + c * 16 + ln) * 1024;
    short8 wf[32];
#pragma unroll
    for (int kt = 0; kt < 32; kt++) wf[kt] = frag8(Wh, whbase + kt * 32 + q * 8, f32);

    const size_t wxbase = (size_t)(g * 1024 + c * 16 + ln) * 512;
    short8 wxf[16];
#pragma unroll
    for (int kt = 0; kt < 16; kt++) wxf[kt] = frag8(Wx, wxbase + kt * 32 + q * 8, f32);

    if (tid < 128) hown[tid >> 4][tid & 15] = 0.f;
    if (tid < 48) {
        int gg = tid >> 4, jj = tid & 15;
        bxs[gg][jj] = ldf(bx, gg * 1024 + c * 16 + jj, f32);
        bhs[gg][jj] = ldf(bh, gg * 1024 + c * 16 + jj, f32);
    }
    __syncthreads();

    for (int t = 0; t < 512; t++) {
        // phase base: [phase][pl][group]; read phase t&1, write phase (t&1)^1
        const short* hsrc = hb + (size_t)(t & 1) * 131072 + gb * 8192;
        short*       hdst = hb + (size_t)((t & 1) ^ 1) * 131072 + gb * 8192;

        float4v ax = (float4v){0.f,0.f,0.f,0.f};
        float4v ah = (float4v){0.f,0.f,0.f,0.f};

        // ===== stage x_t (8 rows x 512) -> xs (vectorized loads, r-swizzled LDS)
#pragma unroll
        for (int i = 0; i < 3; i++) { int e = tid + i * 192; if (e < 512) {
            int kb = e & 63, r = e >> 6;
            size_t gi = (size_t)(gb * 8 + r) * 262144 + (size_t)t * 512 + kb * 8;
            short8 v = frag8(inputs, gi, f32);
            *(short8*)((char*)xs + kb * 128 + ((r ^ (kb & 7)) << 4)) = v;
        } }

        // ===== resolve OWN GROUP's 64 flags (monotone; one contiguous 256B line)
        if (t && tid < 64) {
            const unsigned* fp = &cnt[gb * 64 + tid];
            while (__hip_atomic_load(fp, __ATOMIC_RELAXED, __HIP_MEMORY_SCOPE_AGENT) < (unsigned)t)
                __builtin_amdgcn_s_sleep(2);
        }
        __syncthreads();

        // ===== issue ALL h loads (hi+lo, 32 KB, sc1); x-MFMA hides the latency
        unsigned long long rv[11][2];
#pragma unroll
        for (int i = 0; i < 11; i++) { int e = tid + i * 192; if (e < 2048) {
            const unsigned long long* p_ = (const unsigned long long*)
                (hsrc + (size_t)(e >> 10) * 65536 + (size_t)(e & 1023) * 8);
            rv[i][0] = __hip_atomic_load(p_,     __ATOMIC_RELAXED, __HIP_MEMORY_SCOPE_AGENT);
            rv[i][1] = __hip_atomic_load(p_ + 1, __ATOMIC_RELAXED, __HIP_MEMORY_SCOPE_AGENT);
        } }

#pragma unroll
        for (int kt = 0; kt < 16; kt++) {
            int kb = kt * 4 + q;
            short8 a = *(const short8*)((const char*)xs + kb * 128 + ((lr ^ (kb & 7)) << 4));
            ax = __builtin_amdgcn_mfma_f32_16x16x32_bf16(a, wxf[kt], ax, 0, 0, 0);
        }

#pragma unroll
        for (int i = 0; i < 11; i++) { int e = tid + i * 192; if (e < 2048) {
            int pl = e >> 10, u = e & 1023, kb = u >> 3, r = u & 7;
            union { unsigned long long qq[2]; short8 v; } u_;
            u_.qq[0] = rv[i][0]; u_.qq[1] = rv[i][1];
            *(short8*)((char*)&hs[pl][0] + kb * 128 + ((r ^ (kb & 7)) << 4)) = u_.v;
        } }
        __syncthreads();

        // ===== h MFMA: hi plane then lo plane, same wf[kt] (h = hi + lo)
#pragma unroll
        for (int pl = 0; pl < 2; pl++)
#pragma unroll
            for (int kt = 0; kt < 32; kt++) {
                int kb = kt * 4 + q;
                short8 a = *(const short8*)((const char*)&hs[pl][0] + kb * 128 + ((lr ^ (kb & 7)) << 4));
                ah = __builtin_amdgcn_mfma_f32_16x16x32_bf16(a, wf[kt], ah, 0, 0, 0);
            }

        // ===== accumulators -> LDS (C/D: col = lane&15, row = (lane>>4)*4 + reg; rows 0-7 valid)
        if (q < 2) {
#pragma unroll
            for (int r = 0; r < 4; r++) {
                Px[g][q * 4 + r][ln] = ax[r];
                Ph[g][q * 4 + r][ln] = ah[r];
            }
        }
        __syncthreads();

        // ===== gates + h update (8 rows x 16 cols)
        if (tid < 128) {
            int r = tid >> 4, jj = tid & 15;
            float xr = Px[0][r][jj] + bxs[0][jj];
            float xu = Px[1][r][jj] + bxs[1][jj];
            float xn = Px[2][r][jj] + bxs[2][jj];
            float pr = Ph[0][r][jj] + bhs[0][jj];
            float pu = Ph[1][r][jj] + bhs[1][jj];
            float pn = Ph[2][r][jj] + bhs[2][jj];
            float rg = 1.f / (1.f + __expf(-(xr + pr)));
            float ug = 1.f / (1.f + __expf(-(xu + pu)));
            float ng = tanhf(xn + rg * pn);
            float hy = ug * hown[r][jj] + (1.f - ug) * ng;
            hown[r][jj] = hy;
            size_t b = (size_t)(gb * 8 + r);
            size_t hidx = (b * 512 + t) * 1024 + c * 16 + jj;
            if (f32) ((float*)hid)[hidx] = hy;
            else     ((short*)hid)[hidx] = f2bf(hy);
        }
        __syncthreads();

        // ===== h out (wave 0 only): own 16 cols (kb = 2c, 2c+1), hi+lo, sc1 16B
        if (tid < 32) {
            int r = tid & 7, kbl = (tid >> 3) & 1, pl = tid >> 4;
            union { unsigned long long qq[2]; short8 v; } u;
#pragma unroll
            for (int j = 0; j < 8; j++) {
                float hy = hown[r][kbl * 8 + j];
                short hh = f2bf(hy);
                u.v[j] = pl ? f2bf(hy - bf2f(hh)) : hh;
            }
            unsigned long long* dp = (unsigned long long*)
                (hdst + (size_t)pl * 65536 + (size_t)(2 * c + kbl) * 64 + r * 8);
            __hip_atomic_store(dp,     u.qq[0], __ATOMIC_RELAXED, __HIP_MEMORY_SCOPE_AGENT);
            __hip_atomic_store(dp + 1, u.qq[1], __ATOMIC_RELAXED, __HIP_MEMORY_SCOPE_AGENT);
        }
        // wave0's vmcnt(0) drains all h-out stores (they are all in wave 0)
        asm volatile("s_waitcnt vmcnt(0)" ::: "memory");

        // ===== arrive: monotone flag (no fence, no barrier needed after wave0 drain)
        if (tid == 0)
            __hip_atomic_store(&cnt[gb * 64 + c], (unsigned)(t + 1),
                               __ATOMIC_RELAXED, __HIP_MEMORY_SCOPE_AGENT);
    }
}

extern "C" void kernel_launch(void* const* d_in, const int* in_sizes, int n_in,
                              void* d_out, int out_size, void* d_ws, size_t ws_size,
                              hipStream_t stream)
{
    const void* inputs = d_in[0];
    const void* Wx     = d_in[1];
    const void* bx     = d_in[2];
    const void* Wh     = d_in[3];
    const void* bh     = d_in[4];
    const void* Wo     = d_in[5];
    const void* bo     = d_in[6];

    const size_t HID_ELEMS = (size_t)64 * 512 * 1024;   // 33,554,432

    short* hb; unsigned* cnt; unsigned* flag;
    const bool use_ws = (d_ws != nullptr) && (ws_size >= (size_t)(4096 + 4 * 65536 * 2));
    if (use_ws) {
        cnt  = (unsigned*)d_ws;                  // 512 u32: flags[8][64] monotone
        flag = cnt + 512;                        // 1 u32
        hb   = (short*)((char*)d_ws + 4096);     // 512 KiB, 16B-aligned
    } else {
        short* outh = (short*)d_out + HID_ELEMS;
        hb   = outh;
        cnt  = (unsigned*)(outh + 4 * 65536);
        flag = nullptr;
    }

    if (use_ws) detect_dtype<<<1, 64, 0, stream>>>((const unsigned short*)inputs, flag);
    init_scratch<<<1024, 256, 0, stream>>>(hb, cnt);

    gru_rec<<<NWG, 192, 0, stream>>>(inputs, Wx, bx, Wh, bh, hb, cnt, flag, d_out);

    // out = hiddens @ Wo^T + bo : (32768 x 1024) @ (1024 x 512)
    gemm_bt<<<dim3(256, 4), 256, 0, stream>>>(d_out, Wo, bo, d_out, HID_ELEMS, flag, 32768, 512, 1024);
}

// Round 11
// 5610.128 us; speedup vs baseline: 1.4346x; 1.4346x over previous
//
#include <hip/hip_runtime.h>
#include <hip/hip_bf16.h>

typedef __attribute__((ext_vector_type(8))) short short8;
typedef __attribute__((ext_vector_type(4))) float float4v;

__device__ __forceinline__ float bf2f(short b) {
    unsigned u = ((unsigned)(unsigned short)b) << 16;
    union { unsigned u; float f; } c; c.u = u; return c.f;
}
__device__ __forceinline__ short f2bf(float f) {
    union { float f; unsigned u; } c; c.f = f;
    unsigned r = 0x7FFFu + ((c.u >> 16) & 1u);
    return (short)((c.u + r) >> 16);
}
// dtype-dispatched scalar load (flag: false=bf16, true=fp32)
__device__ __forceinline__ float ldf(const void* p, size_t i, bool f32) {
    return f32 ? ((const float*)p)[i] : bf2f(((const short*)p)[i]);
}
// dtype-dispatched 8-element MFMA fragment load; f32 path VECTORIZED (2x float4)
__device__ __forceinline__ short8 frag8(const void* p, size_t i, bool f32) {
    short8 r;
    if (f32) {
        const float* q = (const float*)p + i;     // i always 8-aligned at call sites
        float4v a = *(const float4v*)q;
        float4v b = *(const float4v*)(q + 4);
#pragma unroll
        for (int j = 0; j < 4; j++) { r[j] = f2bf(a[j]); r[4 + j] = f2bf(b[j]); }
    } else {
        r = *(const short8*)((const short*)p + i);
    }
    return r;
}

// ---------------- dtype detector: 0 = bf16, 1 = fp32 ----------------
__global__ void detect_dtype(const unsigned short* __restrict__ in, unsigned* __restrict__ flag)
{
    int t = threadIdx.x;  // 64 threads
    int sane = 0;
    for (int i = t; i < 256; i += 64) {
        unsigned e = (in[i] >> 7) & 0xFF;
        sane += (e >= 0x70 && e <= 0x8A) ? 1 : 0;
    }
#pragma unroll
    for (int o = 32; o > 0; o >>= 1) sane += __shfl_down(sane, o);
    if (t == 0) *flag = (sane >= 200) ? 0u : 1u;
}

// ---------------- init scratch (h ping-pong planes + flags) ----------------
__global__ void init_scratch(short* __restrict__ hb, unsigned* __restrict__ cnt)
{
    int i = blockIdx.x * 256 + threadIdx.x;
    if (i < 4 * 65536) hb[i] = 0;
    if (i < 512) cnt[i] = 0;
}

// ---------------- C = A @ B^T + bias, bf16 MFMA, optional fp32 hi/lo split --------
__global__ __launch_bounds__(256, 1) void gemm_bt(
    const void* __restrict__ A, const void* __restrict__ B,
    const void* __restrict__ bias, void* __restrict__ outbase, size_t coff,
    const unsigned* __restrict__ flag, int M, int N, int K)
{
    const bool f32 = flag && (flag[0] != 0u);
    __shared__ short Ah[128][72], Bh[128][72];
    __shared__ short Al[128][72], Bl[128][72];
    const int tid  = threadIdx.x;
    const int wid  = tid >> 6;
    const int lane = tid & 63;
    const int ln = lane & 15, q = lane >> 4;
    const int bm = blockIdx.x * 128, bn = blockIdx.y * 128;
    const int wm = (wid & 1) * 64, wn = (wid >> 1) * 64;

    float4v acc[4][4];
#pragma unroll
    for (int i = 0; i < 4; i++)
#pragma unroll
        for (int j = 0; j < 4; j++) acc[i][j] = (float4v){0.f, 0.f, 0.f, 0.f};

    for (int k0 = 0; k0 < K; k0 += 64) {
#pragma unroll
        for (int c = 0; c < 4; c++) {
            int chunk = tid + c * 256;
            int row = chunk >> 3;
            int kq  = (chunk & 7) * 8;
            size_t ga = (size_t)(bm + row) * K + k0 + kq;
            size_t gb = (size_t)(bn + row) * K + k0 + kq;
            if (f32) {
                const float* Af = (const float*)A;
                const float* Bf = (const float*)B;
#pragma unroll
                for (int j = 0; j < 8; j++) {
                    float av = Af[ga + j], bv = Bf[gb + j];
                    short ah = f2bf(av), bh = f2bf(bv);
                    Ah[row][kq + j] = ah; Al[row][kq + j] = f2bf(av - bf2f(ah));
                    Bh[row][kq + j] = bh; Bl[row][kq + j] = f2bf(bv - bf2f(bh));
                }
            } else {
                *(short8*)&Ah[row][kq] = *(const short8*)((const short*)A + ga);
                *(short8*)&Bh[row][kq] = *(const short8*)((const short*)B + gb);
            }
        }
        __syncthreads();
#pragma unroll
        for (int kt = 0; kt < 2; kt++) {
            short8 avh[4], bvh[4];
#pragma unroll
            for (int i = 0; i < 4; i++) avh[i] = *(const short8*)&Ah[wm + i * 16 + ln][kt * 32 + q * 8];
#pragma unroll
            for (int j = 0; j < 4; j++) bvh[j] = *(const short8*)&Bh[wn + j * 16 + ln][kt * 32 + q * 8];
#pragma unroll
            for (int i = 0; i < 4; i++)
#pragma unroll
                for (int j = 0; j < 4; j++)
                    acc[i][j] = __builtin_amdgcn_mfma_f32_16x16x32_bf16(avh[i], bvh[j], acc[i][j], 0, 0, 0);
            if (f32) {
                short8 avl[4], bvl[4];
#pragma unroll
                for (int i = 0; i < 4; i++) avl[i] = *(const short8*)&Al[wm + i * 16 + ln][kt * 32 + q * 8];
#pragma unroll
                for (int j = 0; j < 4; j++) bvl[j] = *(const short8*)&Bl[wn + j * 16 + ln][kt * 32 + q * 8];
#pragma unroll
                for (int i = 0; i < 4; i++)
#pragma unroll
                    for (int j = 0; j < 4; j++) {
                        acc[i][j] = __builtin_amdgcn_mfma_f32_16x16x32_bf16(avh[i], bvl[j], acc[i][j], 0, 0, 0);
                        acc[i][j] = __builtin_amdgcn_mfma_f32_16x16x32_bf16(avl[i], bvh[j], acc[i][j], 0, 0, 0);
                    }
            }
        }
        __syncthreads();
    }
    // C/D layout: col = lane&15, row = (lane>>4)*4 + reg
#pragma unroll
    for (int j = 0; j < 4; j++) {
        int col = bn + wn + j * 16 + ln;
        float bvv = ldf(bias, col, f32);
#pragma unroll
        for (int i = 0; i < 4; i++) {
#pragma unroll
            for (int r = 0; r < 4; r++) {
                int row = bm + wm + i * 16 + q * 4 + r;
                size_t idx = coff + (size_t)row * N + col;
                float v = acc[i][j][r] + bvv;
                if (f32) ((float*)outbase)[idx] = v;
                else     ((short*)outbase)[idx] = f2bf(v);
            }
        }
    }
}

// ---------------- persistent GRU recurrence: REVERT to proven 256-WG structure ----
// R10 lesson: 512 WGs / 2-per-CU breaks IC absorption of the h exchange
// (FETCH 0.8 -> 13.7 GB, fetch-bound). The 256-WG / 4-group regime keeps h
// IC-resident. This version = R8 structure + serial-chain cuts:
//  (1) hi+lo h-loads merged into ONE volley (one IC round trip, not two),
//  (2) x(t+1) register-prefetched during step t's h phase (x off critical path),
//  (3) barriers 6 -> 4 (x-stage merged with poll barrier; pre-flag barrier
//      dropped: h-out stores are wave-0-only, drained by wave-0's vmcnt(0)
//      before its flag store in program order).
// Protocol (unchanged, proven): sc1/IC-coherent h planes, zero fences,
// two-phase flags cnt[phase][group][c] = t+1, wave-0 64-lane relaxed poll.
#define NWG 256
__global__ __launch_bounds__(192, 1) void gru_rec(
    const void* __restrict__ inputs,   // (64,512,512)
    const void* __restrict__ Wx,       // (3072,512)
    const void* __restrict__ bx,       // 3072
    const void* __restrict__ Wh,       // (3072,1024)
    const void* __restrict__ bh,       // 3072
    short* __restrict__ hb,            // 4 planes of 65536 bf16 (ping hi/lo, pong hi/lo)
    unsigned* __restrict__ cnt,        // 512 u32: flags[2][4][64] (zeroed)
    const unsigned* __restrict__ flag, // dtype flag (may be null -> bf16)
    void* __restrict__ hid)            // (64,512,1024) output 0
{
    const bool f32 = flag && (flag[0] != 0u);
    __shared__ short xs[8192];         // 16 KB: [kb=64][r=16][8], r-swizzled
    __shared__ short hs[2][16384];     // 2 x 32 KB: [pl][kb=128][r=16][8], r-swizzled
    __shared__ float Px[3][16][17];
    __shared__ float Ph[3][16][17];
    __shared__ float hown[16][17];
    __shared__ float bxs[3][16], bhs[3][16];

    const int tid  = threadIdx.x;
    const int w    = blockIdx.x;
    const int gb   = w >> 6;           // batch group 0..3 (rows gb*16 .. gb*16+15)
    const int c    = w & 63;           // column WG (H cols c*16 .. c*16+15 per gate)
    const int g    = tid >> 6;         // 0..2 (gate / wave)
    const int lane = tid & 63;
    const int ln   = lane & 15, q = lane >> 4;

    // Wh / Wx B-fragments in registers: B[k][n]: n=lane&15, k=(lane>>4)*8+j
    const size_t whbase = (size_t)(g * 1024 + c * 16 + ln) * 1024;
    short8 wf[32];
#pragma unroll
    for (int kt = 0; kt < 32; kt++) wf[kt] = frag8(Wh, whbase + kt * 32 + q * 8, f32);

    const size_t wxbase = (size_t)(g * 1024 + c * 16 + ln) * 512;
    short8 wxf[16];
#pragma unroll
    for (int kt = 0; kt < 16; kt++) wxf[kt] = frag8(Wx, wxbase + kt * 32 + q * 8, f32);

    for (int e = tid; e < 256; e += 192) hown[e >> 4][e & 15] = 0.f;
    if (tid < 48) {
        int gg = tid >> 4, jj = tid & 15;
        bxs[gg][jj] = ldf(bx, gg * 1024 + c * 16 + jj, f32);
        bhs[gg][jj] = ldf(bh, gg * 1024 + c * 16 + jj, f32);
    }
    __syncthreads();

    // prologue: prefetch x(0) into registers
    short8 xreg[6];
#pragma unroll
    for (int i = 0; i < 6; i++) { int e = tid + i * 192; if (e < 1024) {
        int kb = e & 63, r = e >> 6;
        xreg[i] = frag8(inputs, (size_t)(gb * 16 + r) * 262144 + kb * 8, f32);
    } }

    for (int t = 0; t < 512; t++) {
        // plane-pair bases: read pair (t&1), write pair (t&1)^1; hi at +0, lo at +65536
        const short* hsrc = hb + (size_t)((t & 1) ? 2 : 0) * 65536 + gb * 16384;
        short*       hdst = hb + (size_t)((t & 1) ? 0 : 2) * 65536 + gb * 16384;

        float4v ax = (float4v){0.f,0.f,0.f,0.f};
        float4v ah = (float4v){0.f,0.f,0.f,0.f};

        // ===== xs <- xreg (prefetched; no global latency on critical path)
#pragma unroll
        for (int i = 0; i < 6; i++) { int e = tid + i * 192; if (e < 1024) {
            int kb = e & 63, r = e >> 6;
            *(short8*)((char*)xs + (kb << 8) + ((r ^ (kb & 15)) << 4)) = xreg[i];
        } }

        // ===== resolve OWN GROUP's 64 flags (wave-0, relaxed); one barrier serves
        // both "xs visible" and "h(t-1) published"
        if (t && tid < 64) {
            const unsigned* fp = &cnt[((t - 1) & 1) * 256 + gb * 64 + tid];
            while (__hip_atomic_load(fp, __ATOMIC_RELAXED, __HIP_MEMORY_SCOPE_AGENT) < (unsigned)t)
                __builtin_amdgcn_s_sleep(2);
        }
        __syncthreads();

        // ===== ONE merged h volley: hi+lo 64 KB, 22 x 16B sc1 loads per thread
        unsigned long long rv[22][2];
#pragma unroll
        for (int i = 0; i < 22; i++) { int e = tid + i * 192; if (e < 4096) {
            const unsigned long long* p_ = (const unsigned long long*)
                (hsrc + (size_t)(e >> 11) * 65536 + (size_t)(e & 2047) * 8);
            rv[i][0] = __hip_atomic_load(p_,     __ATOMIC_RELAXED, __HIP_MEMORY_SCOPE_AGENT);
            rv[i][1] = __hip_atomic_load(p_ + 1, __ATOMIC_RELAXED, __HIP_MEMORY_SCOPE_AGENT);
        } }

        // ===== x-MFMA covers part of the IC round trip
#pragma unroll
        for (int kt = 0; kt < 16; kt++) {
            int kb = kt * 4 + q;
            short8 a = *(const short8*)((const char*)xs + (kb << 8) + ((ln ^ (kb & 15)) << 4));
            ax = __builtin_amdgcn_mfma_f32_16x16x32_bf16(a, wxf[kt], ax, 0, 0, 0);
        }

        // ===== prefetch x(t+1) globals (plain loads; in flight until next step's ds_write)
        {
            int tn = (t < 511) ? (t + 1) : 511;   // clamp: t=511 prefetch unused
#pragma unroll
            for (int i = 0; i < 6; i++) { int e = tid + i * 192; if (e < 1024) {
                int kb = e & 63, r = e >> 6;
                xreg[i] = frag8(inputs, (size_t)(gb * 16 + r) * 262144 + (size_t)tn * 512 + kb * 8, f32);
            } }
        }

        // ===== write hs (reg deps insert staged vmcnt waits for the h volley only)
#pragma unroll
        for (int i = 0; i < 22; i++) { int e = tid + i * 192; if (e < 4096) {
            int pl = e >> 11, u = e & 2047, kb = u >> 4, r = u & 15;
            union { unsigned long long qq[2]; short8 v; } u_;
            u_.qq[0] = rv[i][0]; u_.qq[1] = rv[i][1];
            *(short8*)((char*)&hs[pl][0] + (kb << 8) + ((r ^ (kb & 15)) << 4)) = u_.v;
        } }
        __syncthreads();

        // ===== h MFMA: hi plane then lo plane, same wf[kt] (h = hi + lo)
#pragma unroll
        for (int pl = 0; pl < 2; pl++)
#pragma unroll
            for (int kt = 0; kt < 32; kt++) {
                int kb = kt * 4 + q;
                short8 a = *(const short8*)((const char*)&hs[pl][0] + (kb << 8) + ((ln ^ (kb & 15)) << 4));
                ah = __builtin_amdgcn_mfma_f32_16x16x32_bf16(a, wf[kt], ah, 0, 0, 0);
            }

        // ===== accumulators -> LDS (C/D: col = lane&15, row = (lane>>4)*4 + reg)
#pragma unroll
        for (int r = 0; r < 4; r++) {
            Px[g][q * 4 + r][ln] = ax[r];
            Ph[g][q * 4 + r][ln] = ah[r];
        }
        __syncthreads();

        // ===== gates + h update (16 rows x 16 cols per WG)
        for (int e = tid; e < 256; e += 192) {
            int r = e >> 4, jj = e & 15;
            float xr = Px[0][r][jj] + bxs[0][jj];
            float xu = Px[1][r][jj] + bxs[1][jj];
            float xn = Px[2][r][jj] + bxs[2][jj];
            float pr = Ph[0][r][jj] + bhs[0][jj];
            float pu = Ph[1][r][jj] + bhs[1][jj];
            float pn = Ph[2][r][jj] + bhs[2][jj];
            float rg = 1.f / (1.f + __expf(-(xr + pr)));
            float ug = 1.f / (1.f + __expf(-(xu + pu)));
            float ng = tanhf(xn + rg * pn);
            float hy = ug * hown[r][jj] + (1.f - ug) * ng;
            hown[r][jj] = hy;
            size_t b = (size_t)(gb * 16 + r);
            size_t hidx = (b * 512 + t) * 1024 + c * 16 + jj;
            if (f32) ((float*)hid)[hidx] = hy;
            else     ((short*)hid)[hidx] = f2bf(hy);
        }
        __syncthreads();

        // ===== h out (wave 0 only): own 16 cols (kb = 2c, 2c+1), hi+lo, sc1 16B
        if (tid < 64) {
            int r = tid & 15, kbl = (tid >> 4) & 1, pl = tid >> 5;
            union { unsigned long long qq[2]; short8 v; } u;
#pragma unroll
            for (int j = 0; j < 8; j++) {
                float hy = hown[r][kbl * 8 + j];
                short hh = f2bf(hy);
                u.v[j] = pl ? f2bf(hy - bf2f(hh)) : hh;
            }
            unsigned long long* dp = (unsigned long long*)
                (hdst + (size_t)pl * 65536 + (size_t)(2 * c + kbl) * 128 + r * 8);
            __hip_atomic_store(dp,     u.qq[0], __ATOMIC_RELAXED, __HIP_MEMORY_SCOPE_AGENT);
            __hip_atomic_store(dp + 1, u.qq[1], __ATOMIC_RELAXED, __HIP_MEMORY_SCOPE_AGENT);
        }
        // wave-0's vmcnt(0) drains its h-out stores; flag store follows in program
        // order. No barrier needed: waves 1/2 only touch xs next (no hazard) and
        // block at the next step's first barrier until wave 0 arrives.
        asm volatile("s_waitcnt vmcnt(0)" ::: "memory");
        if (tid == 0)
            __hip_atomic_store(&cnt[(t & 1) * 256 + gb * 64 + c], (unsigned)(t + 1),
                               __ATOMIC_RELAXED, __HIP_MEMORY_SCOPE_AGENT);
    }
}

extern "C" void kernel_launch(void* const* d_in, const int* in_sizes, int n_in,
                              void* d_out, int out_size, void* d_ws, size_t ws_size,
                              hipStream_t stream)
{
    const void* inputs = d_in[0];
    const void* Wx     = d_in[1];
    const void* bx     = d_in[2];
    const void* Wh     = d_in[3];
    const void* bh     = d_in[4];
    const void* Wo     = d_in[5];
    const void* bo     = d_in[6];

    const size_t HID_ELEMS = (size_t)64 * 512 * 1024;   // 33,554,432

    short* hb; unsigned* cnt; unsigned* flag;
    const bool use_ws = (d_ws != nullptr) && (ws_size >= (size_t)(4096 + 4 * 65536 * 2));
    if (use_ws) {
        cnt  = (unsigned*)d_ws;                  // 512 u32: flags[2][4][64]
        flag = cnt + 512;                        // 1 u32
        hb   = (short*)((char*)d_ws + 4096);     // 512 KiB, 16B-aligned
    } else {
        short* outh = (short*)d_out + HID_ELEMS;
        hb   = outh;
        cnt  = (unsigned*)(outh + 4 * 65536);
        flag = nullptr;
    }

    if (use_ws) detect_dtype<<<1, 64, 0, stream>>>((const unsigned short*)inputs, flag);
    init_scratch<<<1024, 256, 0, stream>>>(hb, cnt);

    gru_rec<<<NWG, 192, 0, stream>>>(inputs, Wx, bx, Wh, bh, hb, cnt, flag, d_out);

    // out = hiddens @ Wo^T + bo : (32768 x 1024) @ (1024 x 512)
    gemm_bt<<<dim3(256, 4), 256, 0, stream>>>(d_out, Wo, bo, d_out, HID_ELEMS, flag, 32768, 512, 1024);
}